// Round 6
// baseline (461.160 us; speedup 1.0000x reference)
//
#include <hip/hip_runtime.h>

// RelationAwareAttention on gfx950.
// wtrans (tiny) -> QKV GEMM (A staged f32->bf16 on the fly, Q pre-scaled by
// SCALING*log2e, V emitted fp16) -> fused relation-aware attention (full 2048-key
// range per block, XCD-group swizzle, SWAPPED QK^T: C[k][q] so relw loads are
// float4 and P writes are packed b32, exp2 scores, fp16 P/V PV-MFMA, in-kernel
// normalize -> AO bf16) -> O GEMM -> LN.

using u16 = unsigned short;
using u32 = unsigned int;

typedef __attribute__((ext_vector_type(8))) short bf16x8;     // 8 bf16 = 4 VGPRs
typedef __attribute__((ext_vector_type(8))) _Float16 f16x8;   // 8 fp16 = 4 VGPRs
typedef __attribute__((ext_vector_type(4))) float f32x4;

#define H_  16
#define NH_ 8
#define HD_ 32
#define L_  2048
#define E_  512
#define B_  2
#define M_  4096           // B_*L_
// SCALING * log2(e): fold into Q so score loop is a single v_exp_f32 (exp2).
static constexpr float QSCALE_ = 0.17677669529663689f * 1.44269504088896340f;

__device__ inline u16 f2bf(float x) {
  union { float f; u32 u; } v; v.f = x;
  u32 r = v.u + 0x7FFFu + ((v.u >> 16) & 1u);   // RNE
  return (u16)(r >> 16);
}
__device__ inline u16 f2h(float x) {
  union { _Float16 h; u16 u; } v; v.h = (_Float16)x; return v.u;
}

// ---------------- weight transpose + bf16 (tiny) ----------------
__global__ __launch_bounds__(256) void k_wtrans(const float* __restrict__ Wq, const float* __restrict__ Wk,
                                                const float* __restrict__ Wv, const float* __restrict__ Wo,
                                                u16* __restrict__ Tq, u16* __restrict__ Tk,
                                                u16* __restrict__ Tv, u16* __restrict__ To) {
  int z = blockIdx.z;
  const float* W = (z == 0) ? Wq : (z == 1) ? Wk : (z == 2) ? Wv : Wo;
  u16* T = (z == 0) ? Tq : (z == 1) ? Tk : (z == 2) ? Tv : To;
  __shared__ u16 tile[64][65];
  int r0 = blockIdx.y * 64, c0 = blockIdx.x * 64;
  int tw = threadIdx.x >> 6, tl = threadIdx.x & 63;
#pragma unroll
  for (int i = 0; i < 16; ++i) {
    int r = i * 4 + tw;
    tile[r][tl] = f2bf(W[(size_t)(r0 + r) * E_ + c0 + tl]);
  }
  __syncthreads();
#pragma unroll
  for (int i = 0; i < 16; ++i) {
    int r = i * 4 + tw;
    T[(size_t)(c0 + r) * E_ + r0 + tl] = tile[tl][r];
  }
}

// ---------------- 64x64 bf16 MFMA GEMM, K=512 ----------------
// 4 waves, each owns a 32x32 output (2x2 of 16x16 frags). K-step 64.
// AF32=1: A is fp32 [M,512], converted to bf16 during LDS staging.
// EPI 0:  write u16 head layout [B,H,L,HD] via per-wave LDS transpose (oscale,
//         ofmt: 0=bf16, 1=fp16).
// EPI 1:  write fp32 [M,512] + bias.
template <int AF32, int EPI>
__device__ inline void gemm_body(const void* __restrict__ A, const u16* __restrict__ Bt,
                                 const float* __restrict__ bias, void* __restrict__ out,
                                 float oscale, int ofmt) {
  __shared__ __align__(16) u16 smem[2 * 64 * 72];   // As | Bs
  u16* As = smem;
  u16* Bs = smem + 64 * 72;
  const int tid = threadIdx.x;
  const int lane = tid & 63, wid = tid >> 6;
  const int m0 = blockIdx.x * 64, n0 = blockIdx.y * 64;
  const int wm = (wid >> 1) * 32, wn = (wid & 1) * 32;
  const int mrow = lane & 15, quad = lane >> 4;
  f32x4 acc[2][2] = {};
  for (int k0 = 0; k0 < 512; k0 += 64) {
    __syncthreads();
#pragma unroll
    for (int i = 0; i < 2; ++i) {
      int task = i * 256 + tid;
      int r = task >> 3, c = task & 7;
      *(uint4*)(Bs + r * 72 + c * 8) = *(const uint4*)(Bt + (size_t)(n0 + r) * 512 + k0 + c * 8);
      if (AF32) {
        const float* af = (const float*)A + (size_t)(m0 + r) * 512 + k0 + c * 8;
        float4 v0 = *(const float4*)af;
        float4 v1 = *(const float4*)(af + 4);
        u16 o8[8] = {f2bf(v0.x), f2bf(v0.y), f2bf(v0.z), f2bf(v0.w),
                     f2bf(v1.x), f2bf(v1.y), f2bf(v1.z), f2bf(v1.w)};
        *(uint4*)(As + r * 72 + c * 8) = *(const uint4*)o8;
      } else {
        *(uint4*)(As + r * 72 + c * 8) =
            *(const uint4*)((const u16*)A + (size_t)(m0 + r) * 512 + k0 + c * 8);
      }
    }
    __syncthreads();
#pragma unroll
    for (int kk = 0; kk < 64; kk += 32) {
      bf16x8 af[2], bfr[2];
#pragma unroll
      for (int f = 0; f < 2; ++f)
        af[f] = *(const bf16x8*)(As + (wm + f * 16 + mrow) * 72 + kk + quad * 8);
#pragma unroll
      for (int f = 0; f < 2; ++f)
        bfr[f] = *(const bf16x8*)(Bs + (wn + f * 16 + mrow) * 72 + kk + quad * 8);
#pragma unroll
      for (int fm = 0; fm < 2; ++fm)
#pragma unroll
        for (int fn = 0; fn < 2; ++fn)
          acc[fm][fn] = __builtin_amdgcn_mfma_f32_16x16x32_bf16(af[fm], bfr[fn], acc[fm][fn], 0, 0, 0);
    }
  }
  if (EPI == 0) {
    // per-wave LDS transpose -> 16B vector stores to [B,H,L,HD]; the wave's
    // 32-wide n-slice is exactly one head (n0, wn are 32-aligned).
    __syncthreads();                       // all waves done reading As/Bs
    u16* wscr = smem + wid * (32 * 36);    // 32 rows x 36 u16 per wave
#pragma unroll
    for (int fn = 0; fn < 2; ++fn) {
      float bv = bias[n0 + wn + fn * 16 + mrow];
#pragma unroll
      for (int fm = 0; fm < 2; ++fm)
#pragma unroll
        for (int r = 0; r < 4; ++r) {
          float x = (acc[fm][fn][r] + bv) * oscale;
          wscr[(fm * 16 + quad * 4 + r) * 36 + fn * 16 + mrow] = ofmt ? f2h(x) : f2bf(x);
        }
    }
    asm volatile("s_waitcnt lgkmcnt(0)" ::: "memory"); // wave-private scratch
    const int hg = (n0 + wn) >> 5;
    const int row = lane >> 1, j = lane & 1;
    int gm = m0 + wm + row;
    int bb = gm >> 11, q = gm & (L_ - 1);
    u16* dst = (u16*)out + (((size_t)(bb * H_ + hg)) * L_ + q) * HD_ + j * 16;
    uint4 v0 = *(const uint4*)(wscr + row * 36 + j * 16);
    uint4 v1 = *(const uint4*)(wscr + row * 36 + j * 16 + 8);
    *(uint4*)dst = v0;
    *(uint4*)(dst + 8) = v1;
  } else {
#pragma unroll
    for (int fn = 0; fn < 2; ++fn) {
      int gn = n0 + wn + fn * 16 + mrow;
      float bv = bias[gn];
#pragma unroll
      for (int fm = 0; fm < 2; ++fm)
#pragma unroll
        for (int r = 0; r < 4; ++r) {
          int gm = m0 + wm + fm * 16 + quad * 4 + r;
          ((float*)out)[(size_t)gm * E_ + gn] = acc[fm][fn][r] + bv;
        }
    }
  }
}

__global__ __launch_bounds__(256) void k_gemm_qkv(const float* Xq, const float* Xk, const float* Xv,
                                                  const u16* Tq, const u16* Tk, const u16* Tv,
                                                  const float* bq, const float* bk, const float* bv,
                                                  u16* Qb, u16* Kb, u16* Vb) {
  int z = blockIdx.z;
  const float* A = (z == 0) ? Xq : (z == 1) ? Xk : Xv;
  const u16* T = (z == 0) ? Tq : (z == 1) ? Tk : Tv;
  const float* bi = (z == 0) ? bq : (z == 1) ? bk : bv;
  u16* o = (z == 0) ? Qb : (z == 1) ? Kb : Vb;
  float os = (z == 0) ? QSCALE_ : 1.0f;   // fold SCALING*log2e into Q
  int of = (z == 2) ? 1 : 0;              // V emitted fp16 for f16 PV-MFMA
  gemm_body<1, 0>(A, T, bi, o, os, of);
}

__global__ __launch_bounds__(256) void k_gemm_o(const u16* AO, const u16* T, const float* bi,
                                                float* Y) {
  gemm_body<0, 1>(AO, T, bi, Y, 1.0f, 0);
}

// ---------------- fused relation-aware attention (full key range) ----------------
// grid (32, 16, 2) = 1024 blocks, XCD-group swizzled: each XCD owns 4 complete
// (b,h) groups so K/V (256 KB/group) stay resident in its L2.
// 256 threads = 4 waves; wave w owns q rows q0+w*16..+15, covers all 2048 keys
// (32 tiles), normalizes in-register and writes final AO bf16 [M,E].
// SWAPPED QK^T: sc = mfma(K, Q) gives C[k=quad*4+r][q=mrow], so a lane's 4 score
// values are CONSECUTIVE in k -> relw loads are one float4 per f, P writes are
// 2 packed b32 per f (row-contiguous), den is a per-lane scalar reduced with 2
// shfl_xor. PV-side P layout/reads unchanged: P[q][k] in Ps[wid].
// Hazards: rwf[] consumed by the score loop, so next tile's LOAD_REL is issued
// only AFTER it (WAR-safe); rA/rB flushed to LDS in WRITE() before LOAD_KV.
__global__ __launch_bounds__(256) void k_attn(const u16* __restrict__ Qb, const u16* __restrict__ Kb,
                                              const u16* __restrict__ Vb, const float* __restrict__ relw,
                                              u16* __restrict__ AO) {
  const int tid = threadIdx.x, lane = tid & 63, wid = tid >> 6;
  const int lid = blockIdx.x + 32 * blockIdx.y + 512 * blockIdx.z;
  const int xcd = lid & 7, rest = lid >> 3;
  const int qb = rest & 31, ghi = rest >> 5;
  const int g = ghi * 8 + xcd;            // 0..31
  const int h = g & 15, b = g >> 4;
  const int q0 = qb * 64;
  const bool isrel = (h >= NH_);
  const size_t headOff = ((size_t)(b * H_ + h)) * L_ * HD_;
  const float* wbase = isrel ? relw + ((size_t)(b * (H_ - NH_) + (h - NH_))) * L_ * L_ : nullptr;

  __shared__ __align__(16) u16 Ks[64 * 40];
  __shared__ __align__(16) u16 Vts[32 * 72];    // V tile transposed [d][k], fp16
  __shared__ __align__(16) u16 Ps[4][16 * 72];  // per-wave P[q][k], fp16

  const int mrow = lane & 15, quad = lane >> 4;
  // Q fragment directly from global (coalesced 16B/lane)
  bf16x8 qa = *(const bf16x8*)(Qb + headOff + (size_t)(q0 + wid * 16 + mrow) * HD_ + quad * 8);
  f32x4 accd[2] = {};
  float dens = 0.f;

  // prefetch registers
  uint4 rA, rB;       // V pair (waves 0-1) or K pair (waves 2-3)
  float4 rwf[4];      // relw[q=mrow][kt + f*16 + quad*4 .. +3] (rel heads)
  const int vp = tid >> 2, vc = tid & 3;  // V mapping (tid < 128)
  const int t2 = tid - 128;               // K mapping (tid >= 128)
  const float* wrow = isrel ? wbase + (size_t)(q0 + wid * 16 + mrow) * L_ : nullptr;

  auto LOAD_KV = [&](int kt) {
    if (tid < 128) {
      const u16* vsrc = Vb + headOff + (size_t)(kt + 2 * vp) * HD_ + vc * 8;
      rA = *(const uint4*)(vsrc);
      rB = *(const uint4*)(vsrc + HD_);
    } else {
      int task0 = t2 * 2, task1 = t2 * 2 + 1;
      rA = *(const uint4*)(Kb + headOff + (size_t)(kt + (task0 >> 2)) * HD_ + (task0 & 3) * 8);
      rB = *(const uint4*)(Kb + headOff + (size_t)(kt + (task1 >> 2)) * HD_ + (task1 & 3) * 8);
    }
  };
  auto LOAD_REL = [&](int kt) {
    if (isrel) {
      const float* w2 = wrow + kt + quad * 4;
#pragma unroll
      for (int f = 0; f < 4; ++f) rwf[f] = *(const float4*)(w2 + f * 16);
    }
  };
  auto WRITE = [&]() {
    if (tid < 128) { // V transpose into [d][k]
      const u16* s0 = (const u16*)&rA;
      const u16* s1 = (const u16*)&rB;
#pragma unroll
      for (int i = 0; i < 8; ++i) {
        u32 pk = (u32)s0[i] | ((u32)s1[i] << 16);
        *(u32*)(Vts + (vc * 8 + i) * 72 + 2 * vp) = pk;
      }
    } else {
      int task0 = t2 * 2, task1 = t2 * 2 + 1;
      *(uint4*)(Ks + (task0 >> 2) * 40 + (task0 & 3) * 8) = rA;
      *(uint4*)(Ks + (task1 >> 2) * 40 + (task1 & 3) * 8) = rB;
    }
  };

  LOAD_KV(0);
  LOAD_REL(0);
  for (int kt = 0; kt < L_; kt += 64) {
    __syncthreads();          // previous tile's LDS reads complete
    WRITE();
    if (kt + 64 < L_) LOAD_KV(kt + 64);   // rA/rB already flushed to LDS
    __syncthreads();

    u16* pw = Ps[wid];
#pragma unroll
    for (int f = 0; f < 4; ++f) {
      bf16x8 kb = *(const bf16x8*)(Ks + (f * 16 + mrow) * 40 + quad * 8);
      f32x4 z = {0.f, 0.f, 0.f, 0.f};
      f32x4 sc = __builtin_amdgcn_mfma_f32_16x16x32_bf16(kb, qa, z, 0, 0, 0);
      // C: row=quad*4+r (k), col=mrow (q) -> lane's 4 values consecutive in k
      float e0 = exp2f(sc[0]), e1 = exp2f(sc[1]), e2 = exp2f(sc[2]), e3 = exp2f(sc[3]);
      if (isrel) { e0 *= rwf[f].x; e1 *= rwf[f].y; e2 *= rwf[f].z; e3 *= rwf[f].w; }
      dens += (e0 + e1) + (e2 + e3);
      u32 lo = (u32)f2h(e0) | ((u32)f2h(e1) << 16);
      u32 hi = (u32)f2h(e2) | ((u32)f2h(e3) << 16);
      *(u32*)(pw + mrow * 72 + f * 16 + quad * 4)     = lo;
      *(u32*)(pw + mrow * 72 + f * 16 + quad * 4 + 2) = hi;
    }
    if (kt + 64 < L_) LOAD_REL(kt + 64);  // rwf consumed above -> WAR-safe
    asm volatile("s_waitcnt lgkmcnt(0)" ::: "memory"); // P visible (wave-private tile)
#pragma unroll
    for (int kk = 0; kk < 2; ++kk) {
      f16x8 pa = *(const f16x8*)(pw + mrow * 72 + kk * 32 + quad * 8);
#pragma unroll
      for (int dh = 0; dh < 2; ++dh) {
        f16x8 vhf = *(const f16x8*)(Vts + (dh * 16 + mrow) * 72 + kk * 32 + quad * 8);
        accd[dh] = __builtin_amdgcn_mfma_f32_16x16x32_f16(pa, vhf, accd[dh], 0, 0, 0);
      }
    }
  }

  // dens holds sum over this lane's 16 k-slots for q=mrow; fold quads.
  dens += __shfl_xor(dens, 16, 64);
  dens += __shfl_xor(dens, 32, 64);     // now every lane: den[q=mrow]
  const float eps = isrel ? 1e-6f : 0.f;
  float rinv[4];
#pragma unroll
  for (int r = 0; r < 4; ++r) {
    float d = __shfl(dens, quad * 4 + r, 64);   // den for q=quad*4+r (lanes 0-15)
    rinv[r] = __builtin_amdgcn_rcpf(d + eps);
  }

  // normalize accd (C: row=quad*4+r is q, col=mrow is d), pack, store via LDS
  u16* pw = Ps[wid];
#pragma unroll
  for (int dh = 0; dh < 2; ++dh)
#pragma unroll
    for (int r = 0; r < 4; ++r)
      pw[(quad * 4 + r) * 72 + dh * 16 + mrow] = f2bf(accd[dh][r] * rinv[r]);
  asm volatile("s_waitcnt lgkmcnt(0)" ::: "memory");
  const int row = lane >> 2, j = lane & 3;
  const int qg = q0 + wid * 16 + row;
  *(uint4*)(AO + ((size_t)(b * L_ + qg)) * E_ + h * HD_ + j * 8) =
      *(const uint4*)(pw + row * 72 + j * 8);
}

// ---------------- LayerNorm ----------------
__global__ __launch_bounds__(256) void k_ln(const float* __restrict__ Y, const float* __restrict__ gamma,
                                            const float* __restrict__ beta, float* __restrict__ out) {
  int row = blockIdx.x, tid = threadIdx.x;
  const float* y = Y + (size_t)row * E_;
  float2 v = *(const float2*)(y + tid * 2);
  float s = v.x + v.y, sq = v.x * v.x + v.y * v.y;
#pragma unroll
  for (int off = 1; off < 64; off <<= 1) {
    s += __shfl_xor(s, off, 64);
    sq += __shfl_xor(sq, off, 64);
  }
  __shared__ float ss[4], ssq[4];
  int wid = tid >> 6, lane = tid & 63;
  if (lane == 0) { ss[wid] = s; ssq[wid] = sq; }
  __syncthreads();
  s = ss[0] + ss[1] + ss[2] + ss[3];
  sq = ssq[0] + ssq[1] + ssq[2] + ssq[3];
  float mean = s * (1.f / E_);
  float var = sq * (1.f / E_) - mean * mean;
  float rstd = rsqrtf(var + 1e-5f);
  float2 g = *(const float2*)(gamma + tid * 2);
  float2 be = *(const float2*)(beta + tid * 2);
  float2 o;
  o.x = (v.x - mean) * rstd * g.x + be.x;
  o.y = (v.y - mean) * rstd * g.y + be.y;
  *(float2*)(out + (size_t)row * E_ + tid * 2) = o;
}

extern "C" void kernel_launch(void* const* d_in, const int* in_sizes, int n_in,
                              void* d_out, int out_size, void* d_ws, size_t ws_size,
                              hipStream_t stream) {
  const float* query = (const float*)d_in[0];
  const float* key   = (const float*)d_in[1];
  const float* value = (const float*)d_in[2];
  const float* relw  = (const float*)d_in[3];
  const float* Wq = (const float*)d_in[4];
  const float* bq = (const float*)d_in[5];
  const float* Wk = (const float*)d_in[6];
  const float* bk = (const float*)d_in[7];
  const float* Wv = (const float*)d_in[8];
  const float* bv = (const float*)d_in[9];
  const float* Wo = (const float*)d_in[10];
  const float* bo = (const float*)d_in[11];
  const float* gamma = (const float*)d_in[12];
  const float* beta  = (const float*)d_in[13];

  char* ws = (char*)d_ws;
  u16* Tq = (u16*)(ws + 0);          // 512 KB each (W^T bf16)
  u16* Tk = (u16*)(ws + 524288);
  u16* Tv = (u16*)(ws + 1048576);
  u16* To = (u16*)(ws + 1572864);
  u16* Qb = (u16*)(ws + 2097152);    // 4 MB each, [B,H,L,HD]; Q,K bf16, V fp16
  u16* Kb = (u16*)(ws + 6291456);
  u16* Vb = (u16*)(ws + 10485760);
  u16* AO = (u16*)(ws + 14680064);   // 4 MB, [M,E] bf16 (normalized attn out)
  float* Y = (float*)(ws + 18874368);// 8 MB fp32

  k_wtrans<<<dim3(8, 8, 4), 256, 0, stream>>>(Wq, Wk, Wv, Wo, Tq, Tk, Tv, To);
  k_gemm_qkv<<<dim3(64, 8, 3), 256, 0, stream>>>(query, key, value, Tq, Tk, Tv,
                                                 bq, bk, bv, Qb, Kb, Vb);
  k_attn<<<dim3(32, 16, 2), 256, 0, stream>>>(Qb, Kb, Vb, relw, AO);
  k_gemm_o<<<dim3(64, 8, 1), 256, 0, stream>>>(AO, To, bo, Y);
  k_ln<<<M_, 256, 0, stream>>>(Y, gamma, beta, (float*)d_out);
}